// Round 4
// baseline (606.967 us; speedup 1.0000x reference)
//
#include <hip/hip_runtime.h>

#define AW 132   // padded LDS row width (nW <= 130)

// Fully fused fast guided filter. One block = 4 HR rows x 512 HR cols.
// Recomputes the needed A,b LR support (<=3 rows x <=130 cols) in-block from
// lr_x/lr_y via separable clamped 17x17 box sums (zero-pad OOB + analytic N),
// y-lerps into LDS, then streams hr_x -> out with x-lerp + FMA.
// No workspace, no inter-kernel dependency: pure function of d_in.
__global__ __launch_bounds__(256) void k_fused(
    const float* __restrict__ lrx, const float* __restrict__ lry,
    const float* __restrict__ hr, float* __restrict__ out) {
  const int hl = 512, wl = 512, Hh = 2048, Wh = 2048;

  __shared__ float hX[19][AW], hY[19][AW], hXY[19][AW], hXX[19][AW];
  __shared__ float AL[3][AW], bL[3][AW];
  __shared__ float Ay[4][AW], By[4][AW];

  const int bc = blockIdx.z;
  const int yb = blockIdx.y * 4;    // first HR row
  const int xb = blockIdx.x * 512;  // first HR col
  const int tid = threadIdx.x;

  const float sc = 511.f / 2047.f;  // align-corners scale (same both axes)

  const int x0base = (int)((float)xb * sc);
  const int x0max = (int)((float)(xb + 511) * sc);
  const int nW = x0max - x0base + 2;  // LR cols staged: [x0base, x0max+1], <=130
  const int ylo = (int)((float)yb * sc);
  int yhi = (int)((float)(yb + 3) * sc) + 1;
  if (yhi > hl - 1) yhi = hl - 1;
  const int NR = yhi - ylo + 1;  // LR rows needed, <=3

  const size_t plane = (size_t)bc * hl * wl;
  const float* __restrict__ px = lrx + plane;
  const float* __restrict__ py = lry + plane;

  // ---- Phase 1: horizontal 17-tap sums for 19 LR rows (ylo-8..ylo+10),
  // cols [x0base, x0base+nW). 19 rows x 9 groups of 16 outputs = 171 items.
  if (tid < 171) {
    const int rr = tid / 9;        // 0..18
    const int g = tid - rr * 9;    // 0..8
    const int yr = ylo - 8 + rr;
    float X[32], Y[32];
    if (yr >= 0 && yr < hl) {
      const float* __restrict__ rx = px + (size_t)yr * wl;
      const float* __restrict__ ry = py + (size_t)yr * wl;
      const int gx0 = x0base - 8 + 16 * g;
#pragma unroll
      for (int k = 0; k < 32; ++k) {
        int gx = gx0 + k;
        bool in = (gx >= 0 && gx < wl);
        X[k] = in ? rx[gx] : 0.f;
        Y[k] = in ? ry[gx] : 0.f;
      }
    } else {
#pragma unroll
      for (int k = 0; k < 32; ++k) { X[k] = 0.f; Y[k] = 0.f; }
    }
    float sX = 0.f, sY = 0.f, sXY = 0.f, sXX = 0.f;
#pragma unroll
    for (int k = 0; k < 17; ++k) {
      sX += X[k]; sY += Y[k]; sXY += X[k] * Y[k]; sXX += X[k] * X[k];
    }
#pragma unroll
    for (int j = 0; j < 16; ++j) {
      if (j > 0) {
        sX += X[j + 16] - X[j - 1];
        sY += Y[j + 16] - Y[j - 1];
        sXY += X[j + 16] * Y[j + 16] - X[j - 1] * Y[j - 1];
        sXX += X[j + 16] * X[j + 16] - X[j - 1] * X[j - 1];
      }
      int L = 16 * g + j;
      if (L < nW) {
        hX[rr][L] = sX; hY[rr][L] = sY; hXY[rr][L] = sXY; hXX[rr][L] = sXX;
      }
    }
  }
  __syncthreads();

  // ---- Phase 2: vertical 17-tap + finalize A,b for NR rows x nW cols.
  if (tid < nW) {
    const int c = tid;
    float sX = 0.f, sY = 0.f, sXY = 0.f, sXX = 0.f;
#pragma unroll
    for (int k = 0; k < 17; ++k) {
      sX += hX[k][c]; sY += hY[k][c]; sXY += hXY[k][c]; sXX += hXX[k][c];
    }
    const int gx = x0base + c;
    const int nx = min(gx + 8, wl - 1) - max(gx - 8, 0) + 1;
    for (int ri = 0; ri < NR; ++ri) {
      if (ri > 0) {
        sX += hX[ri + 16][c] - hX[ri - 1][c];
        sY += hY[ri + 16][c] - hY[ri - 1][c];
        sXY += hXY[ri + 16][c] - hXY[ri - 1][c];
        sXX += hXX[ri + 16][c] - hXX[ri - 1][c];
      }
      const int r = ylo + ri;
      const int ny = min(r + 8, hl - 1) - max(r - 8, 0) + 1;
      float inv = 1.f / (float)(nx * ny);
      float mx = sX * inv;
      float my = sY * inv;
      float cov = sXY * inv - mx * my;
      float var = sXX * inv - mx * mx;
      float a = cov / (var + 1e-8f);
      AL[ri][c] = a;
      bL[ri][c] = my - a * mx;
    }
  }
  __syncthreads();

  // ---- Phase 3: y-lerp A,b for the 4 HR rows of this block.
#pragma unroll
  for (int rr = 0; rr < 4; ++rr) {
    float fy = (float)(yb + rr) * sc;
    int y0 = (int)fy;
    if (y0 > hl - 1) y0 = hl - 1;
    int y1 = y0 + 1;
    if (y1 > hl - 1) y1 = hl - 1;
    float wy = fy - (float)y0;
    int l0 = y0 - ylo, l1 = y1 - ylo;
    if (tid < nW) {
      float a0 = AL[l0][tid], a1 = AL[l1][tid];
      float b0 = bL[l0][tid], b1 = bL[l1][tid];
      Ay[rr][tid] = a0 + (a1 - a0) * wy;
      By[rr][tid] = b0 + (b1 - b0) * wy;
    }
  }
  __syncthreads();

  // ---- Phase 4: stream hr -> out with x-lerp + FMA. 512 float4s per block.
  const size_t hrPlane = (size_t)bc * Hh * Wh;
#pragma unroll
  for (int k = 0; k < 2; ++k) {
    const int idx = tid + 256 * k;   // 0..511
    const int rr = idx >> 7;         // HR row within block (128 float4 / row)
    const int c4 = idx & 127;
    const int xg = xb + c4 * 4;
    const size_t o = hrPlane + (size_t)(yb + rr) * Wh + xg;
    const float4 h4 = *(const float4*)(hr + o);
    float4 o4;
#pragma unroll
    for (int j = 0; j < 4; ++j) {
      float fx = (float)(xg + j) * sc;
      int x0 = (int)fx;
      float wx = fx - (float)x0;
      int li = x0 - x0base;
      float a = Ay[rr][li] + (Ay[rr][li + 1] - Ay[rr][li]) * wx;
      float b = By[rr][li] + (By[rr][li + 1] - By[rr][li]) * wx;
      (&o4.x)[j] = a * (&h4.x)[j] + b;
    }
    *(float4*)(out + o) = o4;
  }
}

extern "C" void kernel_launch(void* const* d_in, const int* in_sizes, int n_in,
                              void* d_out, int out_size, void* d_ws, size_t ws_size,
                              hipStream_t stream) {
  const float* lrx = (const float*)d_in[0];
  const float* lry = (const float*)d_in[1];
  const float* hrx = (const float*)d_in[2];
  float* out = (float*)d_out;

  // grid: 4 x-blocks (512 px) x 512 y-blocks (4 rows) x 12 planes
  dim3 grid(2048 / 512, 2048 / 4, 12);
  dim3 block(256);
  k_fused<<<grid, block, 0, stream>>>(lrx, lry, hrx, out);
}

// Round 5
// 386.533 us; speedup vs baseline: 1.5703x; 1.5703x over previous
//
#include <hip/hip_runtime.h>

#define SC (511.f / 2047.f)   // align-corners scale, both axes

// Fully fused fast guided filter, replay-safe (pure function of d_in, no ws).
// One block = 16 HR rows x 512 HR cols. LR support: <=6 rows (+16 halo = 22)
// x <=130 cols (+16 halo = 146, padded to 148). Separable clamped 17x17 box
// sums via zero-pad + analytic N; vertical-first; interleaved LDS layouts.
__global__ __launch_bounds__(256, 3) void k_fused(
    const float* __restrict__ lrx, const float* __restrict__ lry,
    const float* __restrict__ hr, float* __restrict__ out) {
  const int hl = 512, wl = 512, Hh = 2048, Wh = 2048;

  // LDS regions (flat, aliased):
  //  A: stage float2[22][148] = 26048 B; later aliased by ABy float2[16][132]
  //  B: v4 float4[6][148] = 14208 B
  //  C: ABl float2[6][132] = 6336 B            total 46592 B -> 3 blocks/CU
  __shared__ __align__(16) char smem[26048 + 14208 + 6336];
  float2* sxy = (float2*)smem;                    // [22][148] (x,y)
  float4* v4 = (float4*)(smem + 26048);           // [6][148] (X,Y,XY,XX)
  float2* ABl = (float2*)(smem + 26048 + 14208);  // [6][132] (A,b) at LR rows
  float2* ABy = (float2*)smem;                    // [16][132] y-lerped (A,b)

  const int bc = blockIdx.z;
  const int yb = blockIdx.y * 16;   // first HR row
  const int xb = blockIdx.x * 512;  // first HR col
  const int tid = threadIdx.x;

  const int x0base = (int)((float)xb * SC);
  const int x0max = (int)((float)(xb + 511) * SC);
  const int nW = x0max - x0base + 2;  // LR cols produced, <=130
  const int ylo = (int)((float)yb * SC);
  int yhi = (int)((float)(yb + 15) * SC) + 1;
  if (yhi > hl - 1) yhi = hl - 1;
  const int NR = yhi - ylo + 1;  // LR rows produced, <=6

  const size_t plane = (size_t)bc * hl * wl;
  const float* __restrict__ px = lrx + plane;
  const float* __restrict__ py = lry + plane;

  // ---- Phase 0: stage 22 x 148 (x,y), zero outside image (clamped-window
  // semantics via zero-pad + analytic N). All 22*148 words written.
  for (int i = tid; i < 22 * 148; i += 256) {
    int r = i / 148, c = i - r * 148;
    int gy = ylo - 8 + r, gx = x0base - 8 + c;
    float vx = 0.f, vy = 0.f;
    if (gy >= 0 && gy < hl && gx >= 0 && gx < wl) {
      size_t o = (size_t)gy * wl + gx;
      vx = px[o];
      vy = py[o];
    }
    sxy[i] = make_float2(vx, vy);
  }
  __syncthreads();

  // ---- Phase 1: vertical 17-tap sums of x,y,xy,xx for NR rows, all 148 cols.
  for (int c = tid; c < 148; c += 256) {
    float2 s[22];
#pragma unroll
    for (int k = 0; k < 22; ++k) s[k] = sxy[k * 148 + c];
    float sX = 0.f, sY = 0.f, sXY = 0.f, sXX = 0.f;
#pragma unroll
    for (int k = 0; k < 17; ++k) {
      sX += s[k].x;
      sY += s[k].y;
      sXY += s[k].x * s[k].y;
      sXX += s[k].x * s[k].x;
    }
    v4[c] = make_float4(sX, sY, sXY, sXX);
#pragma unroll
    for (int ri = 1; ri < 6; ++ri) {
      if (ri < NR) {
        float2 ad = s[ri + 16], su = s[ri - 1];
        sX += ad.x - su.x;
        sY += ad.y - su.y;
        sXY += ad.x * ad.y - su.x * su.y;
        sXX += ad.x * ad.x - su.x * su.x;
        v4[ri * 148 + c] = make_float4(sX, sY, sXY, sXX);
      }
    }
  }
  __syncthreads();

  // ---- Phase 2: horizontal 17-tap (b128 sliding window) + finalize A,b.
  // Items: NR rows x 33 groups of 4 cols.
  for (int q = tid; q < NR * 33; q += 256) {
    int ri = q / 33, g = q - ri * 33;
    int L0 = 4 * g;
    if (L0 < nW) {
      float4 w[20];
#pragma unroll
      for (int t = 0; t < 20; ++t) w[t] = v4[ri * 148 + L0 + t];
      float sX = 0.f, sY = 0.f, sXY = 0.f, sXX = 0.f;
#pragma unroll
      for (int t = 0; t < 17; ++t) {
        sX += w[t].x;
        sY += w[t].y;
        sXY += w[t].z;
        sXX += w[t].w;
      }
      const int gyr = ylo + ri;
      const int ny = min(gyr + 8, hl - 1) - max(gyr - 8, 0) + 1;
#pragma unroll
      for (int j = 0; j < 4; ++j) {
        if (j > 0) {
          sX += w[j + 16].x - w[j - 1].x;
          sY += w[j + 16].y - w[j - 1].y;
          sXY += w[j + 16].z - w[j - 1].z;
          sXX += w[j + 16].w - w[j - 1].w;
        }
        int L = L0 + j;
        if (L < nW) {
          int gx = x0base + L;
          int nx = min(gx + 8, wl - 1) - max(gx - 8, 0) + 1;
          float inv = 1.f / (float)(nx * ny);
          float mx = sX * inv;
          float my = sY * inv;
          float cov = sXY * inv - mx * my;
          float var = sXX * inv - mx * mx;
          float a = cov / (var + 1e-8f);
          ABl[ri * 132 + L] = make_float2(a, my - a * mx);
        }
      }
    }
  }
  __syncthreads();

  // ---- Phase 3: y-lerp (A,b) for the 16 HR rows; all 16*132 words written.
  for (int q = tid; q < 16 * 132; q += 256) {
    int rr = q / 132, c = q - rr * 132;
    float fy = (float)(yb + rr) * SC;
    int y0 = (int)fy;
    if (y0 > hl - 1) y0 = hl - 1;
    int y1 = y0 + 1;
    if (y1 > hl - 1) y1 = hl - 1;
    float wy = fy - (float)y0;
    int l0 = y0 - ylo, l1 = y1 - ylo;
    int cl = min(c, nW - 1);
    float2 p0 = ABl[l0 * 132 + cl];
    float2 p1 = ABl[l1 * 132 + cl];
    ABy[q] = make_float2(p0.x + (p1.x - p0.x) * wy, p0.y + (p1.y - p0.y) * wy);
  }
  __syncthreads();

  // ---- Phase 4: stream hr -> out. idx = tid + 256k: column (idx&127) fixed
  // per thread, so x-lerp indices/weights are hoisted out of the loop.
  const int c4 = tid & 127;
  const int xg = xb + c4 * 4;
  float wx[4];
  int li0;
  bool hi[4];  // uses upper pair (p1,p2) instead of (p0,p1)
  {
    float fx0 = (float)xg * SC;
    li0 = (int)fx0 - x0base;
#pragma unroll
    for (int j = 0; j < 4; ++j) {
      float fx = (float)(xg + j) * SC;
      int x0 = (int)fx;
      wx[j] = fx - (float)x0;
      hi[j] = (x0 - x0base) != li0;  // at most +1 across 4 px
    }
  }
  const size_t hrPlane = (size_t)bc * Hh * Wh;
#pragma unroll
  for (int k = 0; k < 8; ++k) {
    const int idx = tid + 256 * k;
    const int rr = idx >> 7;  // 0..15
    const size_t o = hrPlane + (size_t)(yb + rr) * Wh + xg;
    const float4 h4 = *(const float4*)(hr + o);
    float2 p0 = ABy[rr * 132 + li0];
    float2 p1 = ABy[rr * 132 + li0 + 1];
    float2 p2 = ABy[rr * 132 + li0 + 2];
    float4 o4;
#pragma unroll
    for (int j = 0; j < 4; ++j) {
      float2 pa = hi[j] ? p1 : p0;
      float2 pb = hi[j] ? p2 : p1;
      float a = pa.x + (pb.x - pa.x) * wx[j];
      float b = pa.y + (pb.y - pa.y) * wx[j];
      (&o4.x)[j] = a * (&h4.x)[j] + b;
    }
    *(float4*)(out + o) = o4;
  }
}

extern "C" void kernel_launch(void* const* d_in, const int* in_sizes, int n_in,
                              void* d_out, int out_size, void* d_ws, size_t ws_size,
                              hipStream_t stream) {
  const float* lrx = (const float*)d_in[0];
  const float* lry = (const float*)d_in[1];
  const float* hrx = (const float*)d_in[2];
  float* out = (float*)d_out;

  // grid: 4 col-blocks (512 px) x 128 row-blocks (16 rows) x 12 planes
  dim3 grid(2048 / 512, 2048 / 16, 12);
  dim3 block(256);
  k_fused<<<grid, block, 0, stream>>>(lrx, lry, hrx, out);
}